// Round 7
// baseline (919.266 us; speedup 1.0000x reference)
//
#include <hip/hip_runtime.h>

#define N_NODES     8192
#define N_FEAT      1024
#define N_FILT      4
#define MAXDEG      8
#define BLK         512     // steps per speculation block

// ---------------------------------------------------------------------------
// Kernel A: filtT[f][v] = (relu(X @ W1^T + b1) @ W2^T + b2)[v][f]
// ---------------------------------------------------------------------------
__global__ __launch_bounds__(256) void filt_kernel(
    const float* __restrict__ X, const float* __restrict__ W1,
    const float* __restrict__ b1, const float* __restrict__ W2,
    const float* __restrict__ b2, float* __restrict__ filtT)
{
    const int node = blockIdx.x * 8 + (threadIdx.x >> 5);
    const int h    = threadIdx.x & 31;
    const float* xr = X  + (size_t)node * N_FEAT;
    const float* wr = W1 + (size_t)h    * N_FEAT;
    float acc = 0.f;
    for (int j = 0; j < N_FEAT; j += 4) {
        float4 xv = *reinterpret_cast<const float4*>(xr + j);
        float4 wv = *reinterpret_cast<const float4*>(wr + j);
        acc += xv.x * wv.x + xv.y * wv.y + xv.z * wv.z + xv.w * wv.w;
    }
    float hv = fmaxf(acc + b1[h], 0.f);
    #pragma unroll
    for (int fo = 0; fo < N_FILT; ++fo) {
        float v = hv * W2[fo * 32 + h];
        for (int off = 16; off; off >>= 1) v += __shfl_xor(v, off, 32);
        if (h == 0) filtT[fo * N_NODES + node] = v + b2[fo];
    }
}

// ---------------------------------------------------------------------------
// Kernel W: wsum[j] = sum_h Wt[h][j] (j=0..7), wsum[8] = sum_h bt[h]
// ---------------------------------------------------------------------------
__global__ void wsum_kernel(const float* __restrict__ Wt,
                            const float* __restrict__ bt,
                            float* __restrict__ wsum)
{
    int t = threadIdx.x;
    if (t < 8) {
        float s = 0.f;
        for (int hh = 0; hh < 64; ++hh) s += Wt[hh * 8 + t];
        wsum[t] = s;
    } else if (t == 8) {
        float s = 0.f;
        for (int hh = 0; hh < 64; ++hh) s += bt[hh];
        wsum[8] = s;
    }
}

// ---------------------------------------------------------------------------
// Kernel R1: partial stable-rank.  512 blocks: f(2b) x scan-chunk cs(2b) x
// vertex-chunk cv(5b).  partial[(f*4+cs)][v] = #{u in chunk cs : (val,u) < (val,v)}
// float4 LDS tile -> 512 b128 reads/thread instead of 8192 scalar.
// ---------------------------------------------------------------------------
__global__ __launch_bounds__(256) void rank_partial_kernel(
    const float* __restrict__ filtT, unsigned short* __restrict__ partial)
{
    const int b  = blockIdx.x;
    const int f  = b >> 7;
    const int cs = (b >> 5) & 3;
    const int cv = b & 31;
    const int v  = (cv << 8) + threadIdx.x;
    const float myv = filtT[(f << 13) + v];

    __shared__ float4 tile[512];
    const float4* src = reinterpret_cast<const float4*>(filtT + (f << 13) + cs * 2048);
    for (int i = threadIdx.x; i < 512; i += 256) tile[i] = src[i];
    __syncthreads();

    int cnt = 0;
    const int ubase = cs * 2048;
    #pragma unroll 4
    for (int j = 0; j < 512; ++j) {
        float4 wv = tile[j];
        int u = ubase + j * 4;
        cnt += (wv.x < myv) || (wv.x == myv && (u + 0) < v);
        cnt += (wv.y < myv) || (wv.y == myv && (u + 1) < v);
        cnt += (wv.z < myv) || (wv.z == myv && (u + 2) < v);
        cnt += (wv.w < myv) || (wv.w == myv && (u + 3) < v);
    }
    partial[((f * 4 + cs) << 13) + v] = (unsigned short)cnt;
}

// ---------------------------------------------------------------------------
// Kernel R2: pos = sum of 4 partials; order[pos] = v.
// ---------------------------------------------------------------------------
__global__ __launch_bounds__(256) void rank_final_kernel(
    const unsigned short* __restrict__ partial,
    unsigned short* __restrict__ pos16, unsigned short* __restrict__ order16)
{
    int g = blockIdx.x * 256 + threadIdx.x;   // 0 .. 32767
    int f = g >> 13, v = g & 8191;
    int r = (int)partial[((f * 4 + 0) << 13) + v]
          + (int)partial[((f * 4 + 1) << 13) + v]
          + (int)partial[((f * 4 + 2) << 13) + v]
          + (int)partial[((f * 4 + 3) << 13) + v];
    pos16[(f << 13) + v] = (unsigned short)r;
    order16[(f << 13) + r] = (unsigned short)v;
}

// ---------------------------------------------------------------------------
// Kernel E: static edge filter.  et[f][s*8+k] = min(pos[dst[order[s]*8+k]], s)
// ---------------------------------------------------------------------------
__global__ __launch_bounds__(256) void etable_kernel(
    const unsigned short* __restrict__ order16,
    const unsigned short* __restrict__ pos16,
    const int* __restrict__ edge_dst,
    unsigned short* __restrict__ et)
{
    const int f  = blockIdx.x >> 5;
    const int e0 = ((blockIdx.x & 31) << 11);
    for (int i = threadIdx.x; i < 2048; i += 256) {
        int e = e0 + i;
        int s = e >> 3, k = e & 7;
        int v = (int)order16[(f << 13) + s];
        int u = edge_dst[v * MAXDEG + k];
        int q = (int)pos16[(f << 13) + u];
        et[(size_t)f * (N_NODES * MAXDEG) + e] = (unsigned short)(q < s ? q : s);
    }
}

// ---------------------------------------------------------------------------
// Kernel B: block-speculative union-find, BLK=512, 512 threads.
// pd[v] = par | (dth<<16); parents strictly decrease.
// Per block: parallel resolve (batched 8-way chase, classify pure/impure,
// pure-attach immediately), ballot-compact impure list, wave-0 pipelined
// serial replay of impure steps only.
// Soundness: snapshot merges are a subset of time-s merges, so
// snapshot-distinct==1 => true-distinct==1 (pure is safe); staleness only
// creates false IMPURE which the replay resolves exactly.
// ---------------------------------------------------------------------------
__device__ __forceinline__ int row8min(int v) {
    int t = min(v, __builtin_amdgcn_mov_dpp(v, 0xB1, 0xF, 0xF, true));   // quad xor1
    t = min(t, __builtin_amdgcn_mov_dpp(t, 0x4E, 0xF, 0xF, true));       // quad xor2
    t = min(t, __builtin_amdgcn_mov_dpp(t, 0x141, 0xF, 0xF, true));      // half mirror
    return t;
}

__global__ __launch_bounds__(512) void persist_kernel(
    const unsigned short* __restrict__ et,      // [N_FILT][N_NODES*8]
    const unsigned short* __restrict__ pos16,   // [N_FILT][N_NODES]
    unsigned short* __restrict__ death16)       // [N_FILT][N_NODES]
{
    const int f    = blockIdx.x;
    const int tid  = threadIdx.x;
    const int lane = tid & 63;
    const int w    = tid >> 6;

    __shared__ unsigned int   s_pd[N_NODES];        // 32 KB packed par|dth
    __shared__ unsigned short s_r16[BLK][8];        // 8 KB snapshot roots
    __shared__ unsigned short s_list[BLK];          // 1 KB impure list
    __shared__ int s_wc[8];
    volatile unsigned int* vpd = s_pd;

    for (int v = tid; v < N_NODES; v += BLK) s_pd[v] = (unsigned)v;  // par=v, dth=0
    __syncthreads();

    const unsigned short* etf = et + (size_t)f * (N_NODES * MAXDEG);

    for (int lo = 0; lo < N_NODES; lo += BLK) {
        const int s = lo + tid;

        // ---- parallel resolve: batched 8-way chase ----
        uint4 raw = *reinterpret_cast<const uint4*>(etf + (size_t)s * 8);
        int e8[8];
        e8[0] = raw.x & 0xffff; e8[1] = raw.x >> 16;
        e8[2] = raw.y & 0xffff; e8[3] = raw.y >> 16;
        e8[4] = raw.z & 0xffff; e8[5] = raw.z >> 16;
        e8[6] = raw.w & 0xffff; e8[7] = raw.w >> 16;

        int pk[8];
        #pragma unroll
        for (int k = 0; k < 8; ++k) pk[k] = e8[k];
        for (;;) {
            int qk[8];
            #pragma unroll
            for (int k = 0; k < 8; ++k) qk[k] = (int)(vpd[pk[k]] & 0xffffu);
            bool done = true;
            #pragma unroll
            for (int k = 0; k < 8; ++k) { done &= (qk[k] == pk[k]); pk[k] = qk[k]; }
            if (done) break;
        }

        int first = -1; bool same = true;
        #pragma unroll
        for (int k = 0; k < 8; ++k) {
            if (e8[k] == s) continue;               // invalid/self edge
            if (first < 0) first = pk[k];
            else same &= (pk[k] == first);
        }
        bool impure = (first >= 0) && !same;
        if (first >= 0 && same)                     // pure: attach, virgin dies at s
            vpd[s] = (unsigned)first | ((unsigned)s << 16);
        if (impure) {
            #pragma unroll
            for (int k = 0; k < 8; ++k) s_r16[tid][k] = (unsigned short)pk[k];
        }

        // ---- compact impure list (ascending s) ----
        unsigned long long bal = __ballot(impure);
        int within = __popcll(bal & ((1ull << lane) - 1ull));
        if (lane == 0) s_wc[w] = __popcll(bal);
        __syncthreads();
        int base = 0, total = 0;
        #pragma unroll
        for (int i = 0; i < 8; ++i) { int c = s_wc[i]; if (i < w) base += c; total += c; }
        if (impure) s_list[base + within] = (unsigned short)tid;
        __syncthreads();

        // ---- wave-0 pipelined serial replay of impure steps ----
        if (tid < 64 && total > 0) {
            int t_cur = (int)s_list[0];
            int p_cur = (int)s_r16[t_cur][lane & 7];
            for (int i = 0; i < total; ++i) {
                int t_nxt = (int)s_list[(i + 1 < total) ? (i + 1) : i];
                int p_nxt = (int)s_r16[t_nxt][lane & 7];   // prefetch (immutable)
                const int sv = lo + t_cur;
                int p = p_cur;                              // stale root: safe start
                for (;;) {
                    int q = (int)(vpd[p] & 0xffffu);
                    if (__all(q == p)) break;
                    p = q;
                }
                int m = row8min(p);                         // elder among current roots
                if (lane < 8 && p != m)                     // kill non-elder roots
                    vpd[p] = (unsigned)m | ((unsigned)sv << 16);
                if (lane == 0)                              // virgin vertex dies (m<sv)
                    vpd[sv] = (unsigned)m | ((unsigned)sv << 16);
                t_cur = t_nxt; p_cur = p_nxt;
            }
        }
        __syncthreads();
    }

    // emit deaths by node id; 0 -> N (undying)
    for (int n = tid; n < N_NODES; n += BLK) {
        int p = (int)pos16[(f << 13) + n];
        int d = (int)(s_pd[p] >> 16);
        death16[(f << 13) + n] = (unsigned short)(d ? d : N_NODES);
    }
}

// ---------------------------------------------------------------------------
// Kernel P: pooled[n] = wsum[8] + sum_f pos_f[n]*wsum[2f] + death_f[n]*wsum[2f+1]
// ---------------------------------------------------------------------------
__global__ __launch_bounds__(256) void pooled_kernel(
    const unsigned short* __restrict__ pos16,
    const unsigned short* __restrict__ death16,
    const float* __restrict__ wsum,
    float* __restrict__ pooled)
{
    int n = blockIdx.x * 256 + threadIdx.x;
    float acc = wsum[8];
    #pragma unroll
    for (int i = 0; i < N_FILT; ++i) {
        acc += (float)pos16[(i << 13) + n]   * wsum[2 * i + 0]
             + (float)death16[(i << 13) + n] * wsum[2 * i + 1];
    }
    pooled[n] = acc;
}

// ---------------------------------------------------------------------------
// Kernel C: out[n][f] = X[n][f] + pooled[n]*Wr[f] + br[f]
// ---------------------------------------------------------------------------
__global__ __launch_bounds__(256) void out_kernel(
    const float* __restrict__ X, const float* __restrict__ Wr,
    const float* __restrict__ br, const float* __restrict__ pooled,
    float* __restrict__ out)
{
    const int node = blockIdx.x;
    const float pl = pooled[node];
    const int fb = threadIdx.x * 4;
    const float4 xv = *reinterpret_cast<const float4*>(X + (size_t)node * N_FEAT + fb);
    const float4 wv = *reinterpret_cast<const float4*>(Wr + fb);
    const float4 bv = *reinterpret_cast<const float4*>(br + fb);
    float4 o;
    o.x = xv.x + pl * wv.x + bv.x;
    o.y = xv.y + pl * wv.y + bv.y;
    o.z = xv.z + pl * wv.z + bv.z;
    o.w = xv.w + pl * wv.w + bv.w;
    *reinterpret_cast<float4*>(out + (size_t)node * N_FEAT + fb) = o;
}

// ---------------------------------------------------------------------------
extern "C" void kernel_launch(void* const* d_in, const int* in_sizes, int n_in,
                              void* d_out, int out_size, void* d_ws, size_t ws_size,
                              hipStream_t stream) {
    const float* X  = (const float*)d_in[0];
    const int* edge = (const int*)d_in[1];
    const float* W1 = (const float*)d_in[2];
    const float* b1 = (const float*)d_in[3];
    const float* W2 = (const float*)d_in[4];
    const float* b2 = (const float*)d_in[5];
    const float* Wt = (const float*)d_in[6];
    const float* bt = (const float*)d_in[7];
    const float* Wr = (const float*)d_in[8];
    const float* br = (const float*)d_in[9];

    const int* edge_dst = edge + N_NODES * MAXDEG;  // row 1 of edge_list

    // ws layout (bytes):
    //   [0,        131072)  filtT    f32[4][8192]
    //   [131072,   196608)  pos16    u16[4][8192]
    //   [196608,   262144)  order16  u16[4][8192]   (aliased as death16 after etable)
    //   [262144,   786432)  et       u16[4][65536]  (first half aliased as partial
    //                                               u16[16][8192] before etable runs)
    //   [786432,   786496)  wsum     f32[16]
    //   [786496,   819264)  pooled   f32[8192]
    char* wsb = (char*)d_ws;
    float*          filtT   = (float*)(wsb);
    unsigned short* pos16   = (unsigned short*)(wsb + 131072);
    unsigned short* order16 = (unsigned short*)(wsb + 196608);
    unsigned short* death16 = (unsigned short*)(wsb + 196608); // alias, later
    unsigned short* partial = (unsigned short*)(wsb + 262144); // alias with et
    unsigned short* et      = (unsigned short*)(wsb + 262144);
    float*          wsum    = (float*)(wsb + 786432);
    float*          pooled  = (float*)(wsb + 786496);

    hipLaunchKernelGGL(filt_kernel,  dim3(N_NODES / 8), dim3(256), 0, stream,
                       X, W1, b1, W2, b2, filtT);
    hipLaunchKernelGGL(wsum_kernel,  dim3(1), dim3(64), 0, stream, Wt, bt, wsum);
    hipLaunchKernelGGL(rank_partial_kernel, dim3(512), dim3(256), 0, stream,
                       filtT, partial);
    hipLaunchKernelGGL(rank_final_kernel, dim3(128), dim3(256), 0, stream,
                       partial, pos16, order16);
    hipLaunchKernelGGL(etable_kernel, dim3(4 * 32), dim3(256), 0, stream,
                       order16, pos16, edge_dst, et);
    hipLaunchKernelGGL(persist_kernel, dim3(N_FILT), dim3(512), 0, stream,
                       et, pos16, death16);
    hipLaunchKernelGGL(pooled_kernel, dim3(N_NODES / 256), dim3(256), 0, stream,
                       pos16, death16, wsum, pooled);
    hipLaunchKernelGGL(out_kernel,   dim3(N_NODES), dim3(256), 0, stream,
                       X, Wr, br, pooled, (float*)d_out);
}

// Round 8
// 640.261 us; speedup vs baseline: 1.4358x; 1.4358x over previous
//
#include <hip/hip_runtime.h>

#define N_NODES     8192
#define N_FEAT      1024
#define N_FILT      4
#define MAXDEG      8
#define BLK         256     // steps per speculation block

// ---------------------------------------------------------------------------
// Kernel A: filtT[f][v] = (relu(X @ W1^T + b1) @ W2^T + b2)[v][f]
// ---------------------------------------------------------------------------
__global__ __launch_bounds__(256) void filt_kernel(
    const float* __restrict__ X, const float* __restrict__ W1,
    const float* __restrict__ b1, const float* __restrict__ W2,
    const float* __restrict__ b2, float* __restrict__ filtT)
{
    const int node = blockIdx.x * 8 + (threadIdx.x >> 5);
    const int h    = threadIdx.x & 31;
    const float* xr = X  + (size_t)node * N_FEAT;
    const float* wr = W1 + (size_t)h    * N_FEAT;
    float acc = 0.f;
    for (int j = 0; j < N_FEAT; j += 4) {
        float4 xv = *reinterpret_cast<const float4*>(xr + j);
        float4 wv = *reinterpret_cast<const float4*>(wr + j);
        acc += xv.x * wv.x + xv.y * wv.y + xv.z * wv.z + xv.w * wv.w;
    }
    float hv = fmaxf(acc + b1[h], 0.f);
    #pragma unroll
    for (int fo = 0; fo < N_FILT; ++fo) {
        float v = hv * W2[fo * 32 + h];
        for (int off = 16; off; off >>= 1) v += __shfl_xor(v, off, 32);
        if (h == 0) filtT[fo * N_NODES + node] = v + b2[fo];
    }
}

// ---------------------------------------------------------------------------
// Kernel W: wsum[j] = sum_h Wt[h][j] (j=0..7), wsum[8] = sum_h bt[h]
// ---------------------------------------------------------------------------
__global__ void wsum_kernel(const float* __restrict__ Wt,
                            const float* __restrict__ bt,
                            float* __restrict__ wsum)
{
    int t = threadIdx.x;
    if (t < 8) {
        float s = 0.f;
        for (int hh = 0; hh < 64; ++hh) s += Wt[hh * 8 + t];
        wsum[t] = s;
    } else if (t == 8) {
        float s = 0.f;
        for (int hh = 0; hh < 64; ++hh) s += bt[hh];
        wsum[8] = s;
    }
}

// ---------------------------------------------------------------------------
// Kernel R1: partial stable-rank. 512 blocks: f(2b) x scan-chunk cs(2b) x
// vertex-chunk cv(5b).
// ---------------------------------------------------------------------------
__global__ __launch_bounds__(256) void rank_partial_kernel(
    const float* __restrict__ filtT, unsigned short* __restrict__ partial)
{
    const int b  = blockIdx.x;
    const int f  = b >> 7;
    const int cs = (b >> 5) & 3;
    const int cv = b & 31;
    const int v  = (cv << 8) + threadIdx.x;
    const float myv = filtT[(f << 13) + v];

    __shared__ float4 tile[512];
    const float4* src = reinterpret_cast<const float4*>(filtT + (f << 13) + cs * 2048);
    for (int i = threadIdx.x; i < 512; i += 256) tile[i] = src[i];
    __syncthreads();

    int cnt = 0;
    const int ubase = cs * 2048;
    #pragma unroll 4
    for (int j = 0; j < 512; ++j) {
        float4 wv = tile[j];
        int u = ubase + j * 4;
        cnt += (wv.x < myv) || (wv.x == myv && (u + 0) < v);
        cnt += (wv.y < myv) || (wv.y == myv && (u + 1) < v);
        cnt += (wv.z < myv) || (wv.z == myv && (u + 2) < v);
        cnt += (wv.w < myv) || (wv.w == myv && (u + 3) < v);
    }
    partial[((f * 4 + cs) << 13) + v] = (unsigned short)cnt;
}

// ---------------------------------------------------------------------------
// Kernel R2: pos = sum of 4 partials; order[pos] = v.
// ---------------------------------------------------------------------------
__global__ __launch_bounds__(256) void rank_final_kernel(
    const unsigned short* __restrict__ partial,
    unsigned short* __restrict__ pos16, unsigned short* __restrict__ order16)
{
    int g = blockIdx.x * 256 + threadIdx.x;   // 0 .. 32767
    int f = g >> 13, v = g & 8191;
    int r = (int)partial[((f * 4 + 0) << 13) + v]
          + (int)partial[((f * 4 + 1) << 13) + v]
          + (int)partial[((f * 4 + 2) << 13) + v]
          + (int)partial[((f * 4 + 3) << 13) + v];
    pos16[(f << 13) + v] = (unsigned short)r;
    order16[(f << 13) + r] = (unsigned short)v;
}

// ---------------------------------------------------------------------------
// Kernel E: static edge filter.  et[f][s*8+k] = min(pos[dst[order[s]*8+k]], s)
// ---------------------------------------------------------------------------
__global__ __launch_bounds__(256) void etable_kernel(
    const unsigned short* __restrict__ order16,
    const unsigned short* __restrict__ pos16,
    const int* __restrict__ edge_dst,
    unsigned short* __restrict__ et)
{
    const int f  = blockIdx.x >> 5;
    const int e0 = ((blockIdx.x & 31) << 11);
    for (int i = threadIdx.x; i < 2048; i += 256) {
        int e = e0 + i;
        int s = e >> 3, k = e & 7;
        int v = (int)order16[(f << 13) + s];
        int u = edge_dst[v * MAXDEG + k];
        int q = (int)pos16[(f << 13) + u];
        et[(size_t)f * (N_NODES * MAXDEG) + e] = (unsigned short)(q < s ? q : s);
    }
}

// ---------------------------------------------------------------------------
// Kernel B: block-speculative union-find with TWO-PASS classification.
// pd[v] = par | (dth<<16); parents strictly decrease (point to older pos).
// Per 256-step block:
//   pass 1 (parallel): batched 8-way chase from et; classify; pure -> attach.
//   barrier (all pure attaches visible)
//   pass 2 (parallel, impure candidates only): re-chase from pass-1 roots
//     (safe: ancestors), reclassify; newly-pure -> attach.
//   compact still-impure list; wave-0 pipelined serial replay (exact).
// Soundness: snapshot merges are a subset of time-s merges, so
// snapshot-distinct==1 => true-distinct==1 (pure attach is always safe);
// staleness only creates false IMPURE, resolved exactly by the replay.
// ---------------------------------------------------------------------------
__device__ __forceinline__ int row8min(int v) {
    int t = min(v, __builtin_amdgcn_mov_dpp(v, 0xB1, 0xF, 0xF, true));   // quad xor1
    t = min(t, __builtin_amdgcn_mov_dpp(t, 0x4E, 0xF, 0xF, true));       // quad xor2
    t = min(t, __builtin_amdgcn_mov_dpp(t, 0x141, 0xF, 0xF, true));      // half mirror
    return t;
}

__global__ __launch_bounds__(256) void persist_kernel(
    const unsigned short* __restrict__ et,      // [N_FILT][N_NODES*8]
    const unsigned short* __restrict__ pos16,   // [N_FILT][N_NODES]
    unsigned short* __restrict__ death16)       // [N_FILT][N_NODES]
{
    const int f    = blockIdx.x;
    const int tid  = threadIdx.x;
    const int lane = tid & 63;
    const int w    = tid >> 6;

    __shared__ unsigned int   s_pd[N_NODES];        // 32 KB packed par|dth
    __shared__ unsigned short s_r16[BLK][8];        // 4 KB replay snapshot roots
    __shared__ unsigned short s_list[BLK];          // impure list
    __shared__ int s_wc[4];
    volatile unsigned int* vpd = s_pd;

    for (int v = tid; v < N_NODES; v += 256) s_pd[v] = (unsigned)v;  // par=v, dth=0
    __syncthreads();

    const unsigned short* etf = et + (size_t)f * (N_NODES * MAXDEG);

    for (int lo = 0; lo < N_NODES; lo += BLK) {
        const int s = lo + tid;

        // ---- pass 1: batched 8-way chase + classify ----
        uint4 raw = *reinterpret_cast<const uint4*>(etf + (size_t)s * 8);
        int e8[8];
        e8[0] = raw.x & 0xffff; e8[1] = raw.x >> 16;
        e8[2] = raw.y & 0xffff; e8[3] = raw.y >> 16;
        e8[4] = raw.z & 0xffff; e8[5] = raw.z >> 16;
        e8[6] = raw.w & 0xffff; e8[7] = raw.w >> 16;

        int pk[8];
        #pragma unroll
        for (int k = 0; k < 8; ++k) pk[k] = e8[k];
        for (;;) {
            int qk[8];
            #pragma unroll
            for (int k = 0; k < 8; ++k) qk[k] = (int)(vpd[pk[k]] & 0xffffu);
            bool done = true;
            #pragma unroll
            for (int k = 0; k < 8; ++k) { done &= (qk[k] == pk[k]); pk[k] = qk[k]; }
            if (done) break;
        }
        int first = -1; bool same = true;
        #pragma unroll
        for (int k = 0; k < 8; ++k) {
            if (e8[k] == s) continue;               // invalid/self edge
            if (first < 0) first = pk[k];
            else same &= (pk[k] == first);
        }
        bool cand = (first >= 0) && !same;          // pass-1 impure candidate
        if (first >= 0 && same)                     // pure: attach, virgin dies at s
            vpd[s] = (unsigned)first | ((unsigned)s << 16);

        __syncthreads();                            // pure attaches now visible

        // ---- pass 2: re-chase candidates from pass-1 roots, reclassify ----
        bool impure = false;
        if (cand) {
            for (;;) {
                int qk[8];
                #pragma unroll
                for (int k = 0; k < 8; ++k) qk[k] = (int)(vpd[pk[k]] & 0xffffu);
                bool done = true;
                #pragma unroll
                for (int k = 0; k < 8; ++k) { done &= (qk[k] == pk[k]); pk[k] = qk[k]; }
                if (done) break;
            }
            int f2 = -1; bool same2 = true;
            #pragma unroll
            for (int k = 0; k < 8; ++k) {
                if (e8[k] == s) continue;
                if (f2 < 0) f2 = pk[k];
                else same2 &= (pk[k] == f2);
            }
            if (same2) {                            // false impure: pure attach now
                vpd[s] = (unsigned)f2 | ((unsigned)s << 16);
            } else {
                impure = true;
                #pragma unroll
                for (int k = 0; k < 8; ++k) s_r16[tid][k] = (unsigned short)pk[k];
            }
        }

        // ---- compact impure list (ascending s) ----
        unsigned long long bal = __ballot(impure);
        int within = __popcll(bal & ((1ull << lane) - 1ull));
        if (lane == 0) s_wc[w] = __popcll(bal);
        __syncthreads();
        int base = 0, total = 0;
        #pragma unroll
        for (int i = 0; i < 4; ++i) { int c = s_wc[i]; if (i < w) base += c; total += c; }
        if (impure) s_list[base + within] = (unsigned short)tid;
        __syncthreads();

        // ---- wave-0 pipelined serial replay of impure steps ----
        if (tid < 64 && total > 0) {
            int t_cur = (int)s_list[0];
            int p_cur = (int)s_r16[t_cur][lane & 7];
            for (int i = 0; i < total; ++i) {
                int t_nxt = (int)s_list[(i + 1 < total) ? (i + 1) : i];
                int p_nxt = (int)s_r16[t_nxt][lane & 7];   // prefetch (immutable)
                const int sv = lo + t_cur;
                int p = p_cur;                              // stale root: safe start
                for (;;) {
                    int q = (int)(vpd[p] & 0xffffu);
                    if (__all(q == p)) break;
                    p = q;
                }
                int m = row8min(p);                         // elder among current roots
                if (lane < 8 && p != m)                     // kill non-elder roots
                    vpd[p] = (unsigned)m | ((unsigned)sv << 16);
                if (lane == 0)                              // virgin vertex dies (m<sv)
                    vpd[sv] = (unsigned)m | ((unsigned)sv << 16);
                t_cur = t_nxt; p_cur = p_nxt;
            }
        }
        __syncthreads();
    }

    // emit deaths by node id; 0 -> N (undying)
    for (int n = tid; n < N_NODES; n += 256) {
        int p = (int)pos16[(f << 13) + n];
        int d = (int)(s_pd[p] >> 16);
        death16[(f << 13) + n] = (unsigned short)(d ? d : N_NODES);
    }
}

// ---------------------------------------------------------------------------
// Kernel C: out[n][f] = X[n][f] + pooled[n]*Wr[f] + br[f], pooled fused:
// pooled[n] = wsum[8] + sum_f pos_f[n]*wsum[2f] + death_f[n]*wsum[2f+1]
// ---------------------------------------------------------------------------
__global__ __launch_bounds__(256) void out_kernel(
    const float* __restrict__ X, const float* __restrict__ Wr,
    const float* __restrict__ br,
    const unsigned short* __restrict__ pos16,
    const unsigned short* __restrict__ death16,
    const float* __restrict__ wsum,
    float* __restrict__ out)
{
    const int node = blockIdx.x;
    float pl = wsum[8];
    #pragma unroll
    for (int i = 0; i < N_FILT; ++i) {
        pl += (float)pos16[(i << 13) + node]   * wsum[2 * i + 0]
            + (float)death16[(i << 13) + node] * wsum[2 * i + 1];
    }
    const int fb = threadIdx.x * 4;
    const float4 xv = *reinterpret_cast<const float4*>(X + (size_t)node * N_FEAT + fb);
    const float4 wv = *reinterpret_cast<const float4*>(Wr + fb);
    const float4 bv = *reinterpret_cast<const float4*>(br + fb);
    float4 o;
    o.x = xv.x + pl * wv.x + bv.x;
    o.y = xv.y + pl * wv.y + bv.y;
    o.z = xv.z + pl * wv.z + bv.z;
    o.w = xv.w + pl * wv.w + bv.w;
    *reinterpret_cast<float4*>(out + (size_t)node * N_FEAT + fb) = o;
}

// ---------------------------------------------------------------------------
extern "C" void kernel_launch(void* const* d_in, const int* in_sizes, int n_in,
                              void* d_out, int out_size, void* d_ws, size_t ws_size,
                              hipStream_t stream) {
    const float* X  = (const float*)d_in[0];
    const int* edge = (const int*)d_in[1];
    const float* W1 = (const float*)d_in[2];
    const float* b1 = (const float*)d_in[3];
    const float* W2 = (const float*)d_in[4];
    const float* b2 = (const float*)d_in[5];
    const float* Wt = (const float*)d_in[6];
    const float* bt = (const float*)d_in[7];
    const float* Wr = (const float*)d_in[8];
    const float* br = (const float*)d_in[9];

    const int* edge_dst = edge + N_NODES * MAXDEG;  // row 1 of edge_list

    // ws layout (bytes):
    //   [0,        131072)  filtT    f32[4][8192]
    //   [131072,   196608)  pos16    u16[4][8192]
    //   [196608,   262144)  order16  u16[4][8192]   (aliased as death16 after etable)
    //   [262144,   786432)  et       u16[4][65536]  (first half aliased as partial)
    //   [786432,   786496)  wsum     f32[16]
    char* wsb = (char*)d_ws;
    float*          filtT   = (float*)(wsb);
    unsigned short* pos16   = (unsigned short*)(wsb + 131072);
    unsigned short* order16 = (unsigned short*)(wsb + 196608);
    unsigned short* death16 = (unsigned short*)(wsb + 196608); // alias, later
    unsigned short* partial = (unsigned short*)(wsb + 262144); // alias with et
    unsigned short* et      = (unsigned short*)(wsb + 262144);
    float*          wsum    = (float*)(wsb + 786432);

    hipLaunchKernelGGL(filt_kernel,  dim3(N_NODES / 8), dim3(256), 0, stream,
                       X, W1, b1, W2, b2, filtT);
    hipLaunchKernelGGL(wsum_kernel,  dim3(1), dim3(64), 0, stream, Wt, bt, wsum);
    hipLaunchKernelGGL(rank_partial_kernel, dim3(512), dim3(256), 0, stream,
                       filtT, partial);
    hipLaunchKernelGGL(rank_final_kernel, dim3(128), dim3(256), 0, stream,
                       partial, pos16, order16);
    hipLaunchKernelGGL(etable_kernel, dim3(4 * 32), dim3(256), 0, stream,
                       order16, pos16, edge_dst, et);
    hipLaunchKernelGGL(persist_kernel, dim3(N_FILT), dim3(256), 0, stream,
                       et, pos16, death16);
    hipLaunchKernelGGL(out_kernel,   dim3(N_NODES), dim3(256), 0, stream,
                       X, Wr, br, pos16, death16, wsum, (float*)d_out);
}